// Round 3
// baseline (7927.922 us; speedup 1.0000x reference)
//
#include <hip/hip_runtime.h>
#include <hip/hip_fp16.h>

#define CN0 200000
#define CN1 100000
#define CN2 50000
#define CM 16
#define CVL 32
#define CK 32
#define CD 64
#define CEPS 1e-12f

// PROFILING ROUND: rep-loops inflate per-dispatch duration so all three
// kernels beat the ~245us harness fills into rocprof top-5. Revert next round.
#define REP_LV0 4
#define REP_C1 5
#define REP_C2 10

__device__ __forceinline__ float lane_bcast(float v, int l) {
    return __int_as_float(__builtin_amdgcn_readlane(__float_as_int(v), l));
}

union U2H4 { uint2 u; __half2 h2[2]; };
union H4 { __half2 h2[2]; uint2 u; };

// Stage 0: ft_lv0[n] = concat(sum_m x[n,m,:], 0.5*(s^2 - sum_m x^2)), fp16 out.
__global__ void k_lv0(const float* __restrict__ x, __half* __restrict__ ft0) {
    int t = blockIdx.x * blockDim.x + threadIdx.x;
    int n = t >> 3;
    int q = t & 7;
    if (n >= CN0) return;
    for (int rep = 0; rep < REP_LV0; ++rep) {
        asm volatile("" ::: "memory");  // force real re-loads each rep
        const float4* xp = reinterpret_cast<const float4*>(x + (size_t)n * (CM * CVL)) + q;
        float4 s = make_float4(0.f, 0.f, 0.f, 0.f);
        float4 sq = make_float4(0.f, 0.f, 0.f, 0.f);
#pragma unroll
        for (int m = 0; m < CM; ++m) {
            float4 v = xp[m * (CVL / 4)];
            s.x += v.x; s.y += v.y; s.z += v.z; s.w += v.w;
            sq.x += v.x * v.x; sq.y += v.y * v.y; sq.z += v.z * v.z; sq.w += v.w * v.w;
        }
        float4 cr;
        cr.x = 0.5f * (s.x * s.x - sq.x);
        cr.y = 0.5f * (s.y * s.y - sq.y);
        cr.z = 0.5f * (s.z * s.z - sq.z);
        cr.w = 0.5f * (s.w * s.w - sq.w);
        uint2* orow = reinterpret_cast<uint2*>(ft0 + (size_t)n * CD);
        H4 pa, pb;
        pa.h2[0] = __floats2half2_rn(s.x, s.y);
        pa.h2[1] = __floats2half2_rn(s.z, s.w);
        pb.h2[0] = __floats2half2_rn(cr.x, cr.y);
        pb.h2[1] = __floats2half2_rn(cr.z, cr.w);
        orow[q] = pa.u;
        orow[8 + q] = pb.u;
    }
}

// Conv level. One wave per node-pair (P=2). Gather: lane l handles dims
// 4h..4h+3 (h=lane&15) of neighbor rows 4t+g (g=lane>>4) -> uint2 loads,
// 4 rows per VMEM instr, 9 instrs/node instead of 33. Cross-group pool
// reduce via shfl_xor(16/32). Matmul: readlane-broadcast, W fp16 in LDS.
template<bool NORM, typename OutT, int REPS>
__launch_bounds__(256, 4)
__global__ void k_conv(const __half* __restrict__ ftin,
                       const int* __restrict__ ids,
                       const int* __restrict__ adj,
                       const float* __restrict__ W,
                       const float* __restrict__ bias,
                       OutT* __restrict__ ftout,
                       int nNodes) {
    __shared__ __half2 Wl2[CD][CD];  // [row-pair][col], 16 KiB
    __shared__ float bl[CD];
    for (int idx = threadIdx.x; idx < CD * CD; idx += blockDim.x) {
        int pair = idx >> 6, col = idx & 63;
        Wl2[pair][col] = __floats2half2_rn(W[(2 * pair) * CD + col],
                                           (W[(2 * pair + 1) * CD + col]));
    }
    if (threadIdx.x < CD) bl[threadIdx.x] = bias[threadIdx.x];
    __syncthreads();

    const int lane = threadIdx.x & 63;
    const int wave = __builtin_amdgcn_readfirstlane(threadIdx.x >> 6);
    const int g = lane >> 4;   // row-group 0..3
    const int h = lane & 15;   // dim-segment 0..15 (dims 4h..4h+3)
    constexpr int P = 2;
    const int batchNodes = (256 / 64) * P;  // 8
    const int nBatches = (nNodes + batchNodes - 1) / batchNodes;

    for (int rep = 0; rep < REPS; ++rep) {
        asm volatile("" ::: "memory");
        for (int batch = blockIdx.x; batch < nBatches; batch += gridDim.x) {
            const int nodeBase =
                __builtin_amdgcn_readfirstlane(batch * batchNodes + wave * P);
            float c0a[P][4], c1a[P][4], acc[P];
            uint2 sv[P];
            int av[P][8];
            uint2 fv[P][8];
            // Phase A: self rows + adjacency ids (all P, loads in flight)
#pragma unroll
            for (int p = 0; p < P; ++p) {
                const int n = nodeBase + p;
                if (n < nNodes) {
                    const int id = ids[n];  // wave-uniform -> s_load
                    sv[p] = *reinterpret_cast<const uint2*>(
                        ftin + ((size_t)id << 6) + (h << 2));
                    const int abase = n * CK;
#pragma unroll
                    for (int t = 0; t < 8; ++t)
                        av[p][t] = adj[abase + 4 * t + g];
                }
            }
            // Phase B: neighbor-feature gathers (all P in flight)
#pragma unroll
            for (int p = 0; p < P; ++p) {
                const int n = nodeBase + p;
                if (n < nNodes) {
#pragma unroll
                    for (int t = 0; t < 8; ++t)
                        fv[p][t] = *reinterpret_cast<const uint2*>(
                            ftin + ((size_t)av[p][t] << 6) + (h << 2));
                }
            }
            // Phase C: accumulate + cross-group reduce + conv vector
#pragma unroll
            for (int p = 0; p < P; ++p) {
                const int n = nodeBase + p;
                float pool4[4] = {0.f, 0.f, 0.f, 0.f};
                float self4[4] = {0.f, 0.f, 0.f, 0.f};
                if (n < nNodes) {
                    float t4[8][4];
#pragma unroll
                    for (int t = 0; t < 8; ++t) {
                        U2H4 u; u.u = fv[p][t];
                        t4[t][0] = __low2float(u.h2[0]);
                        t4[t][1] = __high2float(u.h2[0]);
                        t4[t][2] = __low2float(u.h2[1]);
                        t4[t][3] = __high2float(u.h2[1]);
                    }
#pragma unroll
                    for (int c = 0; c < 4; ++c) {
                        float a01 = t4[0][c] + t4[1][c];
                        float a23 = t4[2][c] + t4[3][c];
                        float a45 = t4[4][c] + t4[5][c];
                        float a67 = t4[6][c] + t4[7][c];
                        float v = (a01 + a23) + (a45 + a67);
                        v += __shfl_xor(v, 16);
                        v += __shfl_xor(v, 32);
                        pool4[c] = v;
                    }
                    U2H4 su; su.u = sv[p];
                    self4[0] = __low2float(su.h2[0]);
                    self4[1] = __high2float(su.h2[0]);
                    self4[2] = __low2float(su.h2[1]);
                    self4[3] = __high2float(su.h2[1]);
                }
#pragma unroll
                for (int c = 0; c < 4; ++c) {
                    c0a[p][c] = self4[c] + pool4[c];
                    c1a[p][c] = self4[c] * pool4[c];
                }
                acc[p] = bl[lane];
            }
            // Matmul: out[j] = b[j] + sum_i c0[i] W[i][j] + c1[i] W[64+i][j]
#pragma unroll
            for (int ii = 0; ii < 32; ++ii) {       // rows 2ii, 2ii+1 (c0 half)
                __half2 w = Wl2[ii][lane];
                float wlo = __low2float(w), whi = __high2float(w);
                const int L = ii >> 1, c = (ii & 1) * 2;
#pragma unroll
                for (int p = 0; p < P; ++p) {
                    acc[p] = fmaf(lane_bcast(c0a[p][c], L), wlo, acc[p]);
                    acc[p] = fmaf(lane_bcast(c0a[p][c + 1], L), whi, acc[p]);
                }
            }
#pragma unroll
            for (int ii = 32; ii < 64; ++ii) {      // rows 64+2(ii-32),.. (c1 half)
                __half2 w = Wl2[ii][lane];
                float wlo = __low2float(w), whi = __high2float(w);
                const int L = (ii - 32) >> 1, c = ((ii - 32) & 1) * 2;
#pragma unroll
                for (int p = 0; p < P; ++p) {
                    acc[p] = fmaf(lane_bcast(c1a[p][c], L), wlo, acc[p]);
                    acc[p] = fmaf(lane_bcast(c1a[p][c + 1], L), whi, acc[p]);
                }
            }
            // Epilogue
#pragma unroll
            for (int p = 0; p < P; ++p) {
                const int n = nodeBase + p;
                if (n >= nNodes) continue;
                float z = fmaxf(acc[p], 0.f);
                if (NORM) {
                    float ss = z * z;
#pragma unroll
                    for (int off = 32; off >= 1; off >>= 1) ss += __shfl_xor(ss, off);
                    float nrm = fmaxf(sqrtf(ss), CEPS);
                    ftout[(size_t)n * CD + lane] = (OutT)(z / nrm);
                } else {
                    ftout[(size_t)n * CD + lane] = (OutT)z;
                }
            }
        }
    }
}

extern "C" void kernel_launch(void* const* d_in, const int* in_sizes, int n_in,
                              void* d_out, int out_size, void* d_ws, size_t ws_size,
                              hipStream_t stream) {
    const float* node_feats  = (const float*)d_in[0];
    const int*   node_l1_ids = (const int*)d_in[1];
    const int*   adj1        = (const int*)d_in[2];
    const int*   node2_pos   = (const int*)d_in[3];
    const int*   adj2        = (const int*)d_in[4];
    const float* W1          = (const float*)d_in[5];
    const float* b1          = (const float*)d_in[6];
    const float* W2          = (const float*)d_in[7];
    const float* b2          = (const float*)d_in[8];
    float* out = (float*)d_out;

    __half* ft0 = (__half*)d_ws;                  // CN0*CD fp16 = 25.6 MB
    __half* ft1 = ft0 + (size_t)CN0 * CD;         // CN1*CD fp16 = 12.8 MB

    int t1 = CN0 * 8;
    k_lv0<<<(t1 + 255) / 256, 256, 0, stream>>>(node_feats, ft0);
    k_conv<false, __half, REP_C1><<<2048, 256, 0, stream>>>(ft0, node_l1_ids, adj1, W1, b1, ft1, CN1);
    k_conv<true, float, REP_C2><<<2048, 256, 0, stream>>>(ft1, node2_pos, adj2, W2, b2, out, CN2);
}

// Round 5
// 3217.089 us; speedup vs baseline: 2.4643x; 2.4643x over previous
//
#include <hip/hip_runtime.h>
#include <hip/hip_fp16.h>

#define CN0 200000
#define CN1 100000
#define CN2 50000
#define CM 16
#define CVL 32
#define CK 32
#define CD 64
#define CEPS 1e-12f

// PROFILING: rep-loops keep all three kernels above the ~245us harness fills
// so they land in rocprof top-5 with counters. Remove once conv is settled.
#define REP_LV0 4
#define REP_C1 5
#define REP_C2 10

typedef _Float16 half2_t __attribute__((ext_vector_type(2)));

__device__ __forceinline__ float lane_bcast(float v, int l) {
    return __int_as_float(__builtin_amdgcn_readlane(__float_as_int(v), l));
}

union H4 { __half2 h2[2]; uint2 u; };

// Stage 0: ft_lv0[n] = concat(sum_m x, 0.5*(s^2 - sum x^2)), fp16 out.
__global__ void k_lv0(const float* __restrict__ x, __half* __restrict__ ft0) {
    int t = blockIdx.x * blockDim.x + threadIdx.x;
    int n = t >> 3;
    int q = t & 7;
    if (n >= CN0) return;
    for (int rep = 0; rep < REP_LV0; ++rep) {
        asm volatile("" ::: "memory");
        const float4* xp = reinterpret_cast<const float4*>(x + (size_t)n * (CM * CVL)) + q;
        float4 s = make_float4(0.f, 0.f, 0.f, 0.f);
        float4 sq = make_float4(0.f, 0.f, 0.f, 0.f);
#pragma unroll
        for (int m = 0; m < CM; ++m) {
            float4 v = xp[m * (CVL / 4)];
            s.x += v.x; s.y += v.y; s.z += v.z; s.w += v.w;
            sq.x += v.x * v.x; sq.y += v.y * v.y; sq.z += v.z * v.z; sq.w += v.w * v.w;
        }
        float4 cr;
        cr.x = 0.5f * (s.x * s.x - sq.x);
        cr.y = 0.5f * (s.y * s.y - sq.y);
        cr.z = 0.5f * (s.z * s.z - sq.z);
        cr.w = 0.5f * (s.w * s.w - sq.w);
        uint2* orow = reinterpret_cast<uint2*>(ft0 + (size_t)n * CD);
        H4 pa, pb;
        pa.h2[0] = __floats2half2_rn(s.x, s.y);
        pa.h2[1] = __floats2half2_rn(s.z, s.w);
        pb.h2[0] = __floats2half2_rn(cr.x, cr.y);
        pb.h2[1] = __floats2half2_rn(cr.z, cr.w);
        orow[q] = pa.u;
        orow[8 + q] = pb.u;
    }
}

// Conv: one wave handles P=4 nodes sequentially. lane -> (g = lane>>5
// row-group, h = lane&31 dim-pair: dims 2h,2h+1). Gather = 16 uint loads
// (rows 2t+g, fp16x2 each) + self uint + scalar adj row. Pool combined
// across the two row-groups by one shfl_xor(32). Conv vector and matmul in
// f32 (fp16 c overflows at level 2: c1 ~ 1e5 > fp16 max). Matmul:
// readlane-broadcast c against f32 W in LDS; lane j owns out[j].
template<bool NORM, typename OutT, int REPS>
__launch_bounds__(256, 4)
__global__ void k_conv(const __half* __restrict__ ftin,
                       const int* __restrict__ ids,
                       const int* __restrict__ adj,
                       const float* __restrict__ W,
                       const float* __restrict__ bias,
                       OutT* __restrict__ ftout,
                       int nNodes) {
    __shared__ float Wl[2 * CD * CD];  // 32 KiB, row-major [128][64]
    __shared__ float bl[CD];
    for (int i = threadIdx.x; i < 2 * CD * CD; i += blockDim.x) Wl[i] = W[i];
    if (threadIdx.x < CD) bl[threadIdx.x] = bias[threadIdx.x];
    __syncthreads();

    const int lane = threadIdx.x & 63;
    const int wave = __builtin_amdgcn_readfirstlane(threadIdx.x >> 6);
    const int g = lane >> 5;          // row-group 0/1
    const int h = lane & 31;          // dim-pair index (dims 2h, 2h+1)
    constexpr int P = 4;
    const int batchNodes = 4 * P;     // 16 nodes per 256-thread block pass
    const int nBatches = (nNodes + batchNodes - 1) / batchNodes;

    for (int rep = 0; rep < REPS; ++rep) {
        asm volatile("" ::: "memory");
        for (int batch = blockIdx.x; batch < nBatches; batch += gridDim.x) {
            const int nodeBase =
                __builtin_amdgcn_readfirstlane(batch * batchNodes + wave * P);
            float c00[P], c01[P], c10[P], c11[P], acc[P];
#pragma unroll
            for (int p = 0; p < P; ++p) {
                const int n = nodeBase + p;   // wave-uniform
                float pa0 = 0.f, pa1 = 0.f, pb0 = 0.f, pb1 = 0.f;
                float s0 = 0.f, s1 = 0.f;
                if (n < nNodes) {             // uniform branch
                    const int id = ids[n];    // s_load
                    uint sv = *reinterpret_cast<const uint*>(
                        ftin + ((size_t)id << 6) + (h << 1));
                    const int* arow = adj + (size_t)n * CK;  // uniform -> s_loads
#pragma unroll
                    for (int t = 0; t < 16; ++t) {
                        const int a0 = arow[2 * t];
                        const int a1 = arow[2 * t + 1];
                        const int at = g ? a1 : a0;          // cndmask
                        uint fvu = *reinterpret_cast<const uint*>(
                            ftin + ((size_t)at << 6) + (h << 1));
                        half2_t v = __builtin_bit_cast(half2_t, fvu);
                        if (t & 1) { pb0 += (float)v.x; pb1 += (float)v.y; }
                        else       { pa0 += (float)v.x; pa1 += (float)v.y; }
                    }
                    half2_t s = __builtin_bit_cast(half2_t, sv);
                    s0 = (float)s.x; s1 = (float)s.y;
                }
                float pool0 = pa0 + pb0;
                float pool1 = pa1 + pb1;
                pool0 += __shfl_xor(pool0, 32);  // combine row-groups
                pool1 += __shfl_xor(pool1, 32);
                c00[p] = s0 + pool0;   // conv row 2h
                c01[p] = s1 + pool1;   // conv row 2h+1
                c10[p] = s0 * pool0;   // conv row 64+2h
                c11[p] = s1 * pool1;   // conv row 64+2h+1
                acc[p] = bl[lane];
            }
            // out[j] = b[j] + sum_i c[i] * W[i][j]; lane = j.
            // c[2i],c[2i+1] live in lane i (i=0..31) as c00/c01; c[64+..] as c10/c11.
#pragma unroll
            for (int i = 0; i < 32; ++i) {
                const float wA = Wl[(2 * i) * CD + lane];
                const float wB = Wl[(2 * i + 1) * CD + lane];
                const float wC = Wl[(CD + 2 * i) * CD + lane];
                const float wD = Wl[(CD + 2 * i + 1) * CD + lane];
#pragma unroll
                for (int p = 0; p < P; ++p) {
                    acc[p] = fmaf(lane_bcast(c00[p], i), wA, acc[p]);
                    acc[p] = fmaf(lane_bcast(c01[p], i), wB, acc[p]);
                    acc[p] = fmaf(lane_bcast(c10[p], i), wC, acc[p]);
                    acc[p] = fmaf(lane_bcast(c11[p], i), wD, acc[p]);
                }
            }
            // Epilogue
#pragma unroll
            for (int p = 0; p < P; ++p) {
                const int n = nodeBase + p;
                if (n >= nNodes) continue;
                float z = fmaxf(acc[p], 0.f);
                if (NORM) {
                    float ss = z * z;
#pragma unroll
                    for (int off = 32; off >= 1; off >>= 1) ss += __shfl_xor(ss, off);
                    float nrm = fmaxf(sqrtf(ss), CEPS);
                    ftout[(size_t)n * CD + lane] = (OutT)(z / nrm);
                } else {
                    ftout[(size_t)n * CD + lane] = (OutT)z;
                }
            }
        }
    }
}

extern "C" void kernel_launch(void* const* d_in, const int* in_sizes, int n_in,
                              void* d_out, int out_size, void* d_ws, size_t ws_size,
                              hipStream_t stream) {
    const float* node_feats  = (const float*)d_in[0];
    const int*   node_l1_ids = (const int*)d_in[1];
    const int*   adj1        = (const int*)d_in[2];
    const int*   node2_pos   = (const int*)d_in[3];
    const int*   adj2        = (const int*)d_in[4];
    const float* W1          = (const float*)d_in[5];
    const float* b1          = (const float*)d_in[6];
    const float* W2          = (const float*)d_in[7];
    const float* b2          = (const float*)d_in[8];
    float* out = (float*)d_out;

    __half* ft0 = (__half*)d_ws;                  // CN0*CD fp16 = 25.6 MB
    __half* ft1 = ft0 + (size_t)CN0 * CD;         // CN1*CD fp16 = 12.8 MB

    int t1 = CN0 * 8;
    k_lv0<<<(t1 + 255) / 256, 256, 0, stream>>>(node_feats, ft0);
    k_conv<false, __half, REP_C1><<<2048, 256, 0, stream>>>(ft0, node_l1_ids, adj1, W1, b1, ft1, CN1);
    k_conv<true, float, REP_C2><<<2048, 256, 0, stream>>>(ft1, node2_pos, adj2, W2, b2, out, CN2);
}

// Round 6
// 247.393 us; speedup vs baseline: 32.0459x; 13.0040x over previous
//
#include <hip/hip_runtime.h>
#include <hip/hip_fp16.h>

#define CN0 200000
#define CN1 100000
#define CN2 50000
#define CM 16
#define CVL 32
#define CK 32
#define CD 64
#define CEPS 1e-12f

__device__ __forceinline__ float lane_bcast(float v, int l) {
    return __int_as_float(__builtin_amdgcn_readlane(__float_as_int(v), l));
}

union H2U { __half2 h2; uint u; };
union H4 { __half2 h2[2]; uint2 u; };

// Stage 0: ft_lv0[n] = concat(sum_m x, 0.5*(s^2 - sum x^2)), fp16 out.
// 8 threads per node, each handles a float4 of the VL=32 dims. HBM-floor.
__global__ void k_lv0(const float* __restrict__ x, __half* __restrict__ ft0) {
    int t = blockIdx.x * blockDim.x + threadIdx.x;
    int n = t >> 3;
    int q = t & 7;
    if (n >= CN0) return;
    const float4* xp = reinterpret_cast<const float4*>(x + (size_t)n * (CM * CVL)) + q;
    float4 s = make_float4(0.f, 0.f, 0.f, 0.f);
    float4 sq = make_float4(0.f, 0.f, 0.f, 0.f);
#pragma unroll
    for (int m = 0; m < CM; ++m) {
        float4 v = xp[m * (CVL / 4)];
        s.x += v.x; s.y += v.y; s.z += v.z; s.w += v.w;
        sq.x += v.x * v.x; sq.y += v.y * v.y; sq.z += v.z * v.z; sq.w += v.w * v.w;
    }
    float4 cr;
    cr.x = 0.5f * (s.x * s.x - sq.x);
    cr.y = 0.5f * (s.y * s.y - sq.y);
    cr.z = 0.5f * (s.z * s.z - sq.z);
    cr.w = 0.5f * (s.w * s.w - sq.w);
    uint2* orow = reinterpret_cast<uint2*>(ft0 + (size_t)n * CD);
    H4 pa, pb;
    pa.h2[0] = __floats2half2_rn(s.x, s.y);
    pa.h2[1] = __floats2half2_rn(s.z, s.w);
    pb.h2[0] = __floats2half2_rn(cr.x, cr.y);
    pb.h2[1] = __floats2half2_rn(cr.z, cr.w);
    orow[q] = pa.u;
    orow[8 + q] = pb.u;
}

// Conv: one wave owns a node's 64-dim row (lane = dim), P=4 nodes per pass.
// Gather: 33 per-lane ushort loads/node in 4 accumulator chains (round-2
// proven structure, no scratch). Matmul in f32 against fp16 W staged in LDS
// (16.6 KB -> 8 blocks/CU; launch_bounds(256,8) caps VGPR at 64 -> 100%
// occupancy; conv is gather-latency-bound so wave count is the lever).
// c stays f32 (fp16 c overflows at level 2: c1 ~ 1e5 > fp16 max).
template<bool NORM, typename OutT>
__launch_bounds__(256, 8)
__global__ void k_conv(const __half* __restrict__ ftin,
                       const int* __restrict__ ids,
                       const int* __restrict__ adj,
                       const float* __restrict__ W,
                       const float* __restrict__ bias,
                       OutT* __restrict__ ftout,
                       int nNodes) {
    __shared__ __half Wt[CD][CD];  // W[i][j]      (i=0..63, "+" half)  8 KiB
    __shared__ __half Wb[CD][CD];  // W[64+i][j]   ("*" half)           8 KiB
    __shared__ float bl[CD];
    for (int idx = threadIdx.x; idx < CD * CD / 2; idx += blockDim.x) {
        const int i = idx >> 5;
        const int jp = (idx & 31) << 1;
        H2U t, b;
        t.h2 = __floats2half2_rn(W[i * CD + jp], W[i * CD + jp + 1]);
        b.h2 = __floats2half2_rn(W[(CD + i) * CD + jp], W[(CD + i) * CD + jp + 1]);
        *reinterpret_cast<uint*>(&Wt[i][jp]) = t.u;
        *reinterpret_cast<uint*>(&Wb[i][jp]) = b.u;
    }
    if (threadIdx.x < CD) bl[threadIdx.x] = bias[threadIdx.x];
    __syncthreads();

    const int lane = threadIdx.x & 63;
    const int wave = __builtin_amdgcn_readfirstlane(threadIdx.x >> 6);
    constexpr int P = 4;
    const int batchNodes = 4 * P;  // 16 nodes per 256-thread block pass
    const int nBatches = (nNodes + batchNodes - 1) / batchNodes;

    for (int batch = blockIdx.x; batch < nBatches; batch += gridDim.x) {
        const int nodeBase =
            __builtin_amdgcn_readfirstlane(batch * batchNodes + wave * P);
        float c0[P], c1[P], acc[P];
#pragma unroll
        for (int p = 0; p < P; ++p) {
            const int n = nodeBase + p;  // wave-uniform
            float n0 = 0.f, pool = 0.f;
            if (n < nNodes) {            // uniform branch
                const int id = ids[n];   // s_load
                n0 = __half2float(ftin[((size_t)id << 6) + lane]);
                const int* arow = adj + (size_t)n * CK;  // uniform -> s_loads
                float q0 = 0.f, q1 = 0.f, q2 = 0.f, q3 = 0.f;
#pragma unroll 8
                for (int k = 0; k < CK; k += 4) {
                    q0 += __half2float(ftin[((size_t)arow[k + 0] << 6) + lane]);
                    q1 += __half2float(ftin[((size_t)arow[k + 1] << 6) + lane]);
                    q2 += __half2float(ftin[((size_t)arow[k + 2] << 6) + lane]);
                    q3 += __half2float(ftin[((size_t)arow[k + 3] << 6) + lane]);
                }
                pool = (q0 + q1) + (q2 + q3);
            }
            c0[p] = n0 + pool;  // conv row `lane`
            c1[p] = n0 * pool;  // conv row 64+`lane`
            acc[p] = bl[lane];
        }
        // out[j] = b[j] + sum_i c0_i*Wt[i][j] + c1_i*Wb[i][j]; lane = j.
#pragma unroll 8
        for (int i = 0; i < CD; ++i) {
            const float wt = __half2float(Wt[i][lane]);
            const float wb = __half2float(Wb[i][lane]);
#pragma unroll
            for (int p = 0; p < P; ++p) {
                acc[p] = fmaf(lane_bcast(c0[p], i), wt, acc[p]);
                acc[p] = fmaf(lane_bcast(c1[p], i), wb, acc[p]);
            }
        }
        // Epilogue
#pragma unroll
        for (int p = 0; p < P; ++p) {
            const int n = nodeBase + p;
            if (n >= nNodes) continue;
            float z = fmaxf(acc[p], 0.f);
            if (NORM) {
                float ss = z * z;
#pragma unroll
                for (int off = 32; off >= 1; off >>= 1) ss += __shfl_xor(ss, off);
                float nrm = fmaxf(sqrtf(ss), CEPS);
                ftout[(size_t)n * CD + lane] = (OutT)(z / nrm);
            } else {
                ftout[(size_t)n * CD + lane] = (OutT)z;
            }
        }
    }
}

extern "C" void kernel_launch(void* const* d_in, const int* in_sizes, int n_in,
                              void* d_out, int out_size, void* d_ws, size_t ws_size,
                              hipStream_t stream) {
    const float* node_feats  = (const float*)d_in[0];
    const int*   node_l1_ids = (const int*)d_in[1];
    const int*   adj1        = (const int*)d_in[2];
    const int*   node2_pos   = (const int*)d_in[3];
    const int*   adj2        = (const int*)d_in[4];
    const float* W1          = (const float*)d_in[5];
    const float* b1          = (const float*)d_in[6];
    const float* W2          = (const float*)d_in[7];
    const float* b2          = (const float*)d_in[8];
    float* out = (float*)d_out;

    __half* ft0 = (__half*)d_ws;                  // CN0*CD fp16 = 25.6 MB
    __half* ft1 = ft0 + (size_t)CN0 * CD;         // CN1*CD fp16 = 12.8 MB

    int t1 = CN0 * 8;
    k_lv0<<<(t1 + 255) / 256, 256, 0, stream>>>(node_feats, ft0);
    k_conv<false, __half><<<2048, 256, 0, stream>>>(ft0, node_l1_ids, adj1, W1, b1, ft1, CN1);
    k_conv<true, float><<<2048, 256, 0, stream>>>(ft1, node2_pos, adj2, W2, b2, out, CN2);
}